// Round 12
// baseline (70.172 us; speedup 1.0000x reference)
//
#include <hip/hip_runtime.h>
#include <hip/hip_bf16.h>

// ECE over logits (8,19,512,1024) f32, labels (8,512,1024) int32.
// R11 = R9/R10 with ONE variable changed: nb -> 256 (1 block/CU, 16 iters/thread).
//   Grid-size curve so far (same core): 2048 blk ~81-87us, 1280 blk 79.8us,
//   512 blk 70.2us -> monotone: fewer resident waves = faster. Mechanism:
//   concurrent DRAM stream count = waves x 19 plane-chunks (2MB apart);
//   fewer streams = better row-buffer locality. Per-wave burst ILP (19-20
//   loads in flight) covers latency even at 1 wave/SIMD.
//   Everything else identical: two-pass full v[19] register core, uint32
//   saddr addressing, 64-replica LDS bins, partial stores, wide finalize.

constexpr int NBINS = 15;
constexpr int NC    = 19;      // classes (fixed by reference)
constexpr int HWSH  = 19;      // H*W = 512*1024 = 2^19 (fixed by reference)

typedef float f32x4 __attribute__((ext_vector_type(4)));
typedef int   i32x4 __attribute__((ext_vector_type(4)));

__global__ __launch_bounds__(256, 5) void ece_partial_kernel(
    const float* __restrict__ logits,
    const int*   __restrict__ labels,
    float*        __restrict__ p_conf,   // [nb*NBINS] per-block conf sums
    unsigned int* __restrict__ p_cnt,    // [nb*NBINS] per-block counts
    unsigned int* __restrict__ p_corr,   // [nb*NBINS] per-block correct counts
    int P4)                              // number of 4-pixel groups
{
    __shared__ unsigned s_mc[NBINS * 64];   // (cnt<<16)|corr per (bin, lane-replica)
    __shared__ float    s_cf[NBINS * 64];   // conf sum per (bin, lane-replica)

    const int t = threadIdx.x;
    for (int i = t; i < NBINS * 64; i += 256) { s_mc[i] = 0u; s_cf[i] = 0.0f; }
    __syncthreads();

    const int lane   = t & 63;
    const unsigned HW = 1u << HWSH;
    const int stride = gridDim.x * 256;

    for (int g = blockIdx.x * 256 + t; g < P4; g += stride) {
        const unsigned p   = (unsigned)g << 2;        // first pixel of this 4-group
        const unsigned n   = p >> HWSH;               // image index
        const unsigned rem = p & (HW - 1);            // h*W + w within the image
        // uint32 ELEMENT offset from the uniform logits base: max (8*19)<<19 < 2^31.
        // Keeps loads in saddr form (SGPR base + 32-bit voffset) -> low VGPR,
        // minimal per-load VALU address work.
        const unsigned base = (n * NC) << HWSH | rem;

        // Load ALL 19 class values for 4 consecutive pixels (burst of 19
        // independent dwordx4 + 1 label load -> max loads-in-flight).
        f32x4 v[NC];
        #pragma unroll
        for (int c = 0; c < NC; ++c)
            v[c] = *reinterpret_cast<const f32x4*>(logits + (base + ((unsigned)c << HWSH)));
        const i32x4 lab = *reinterpret_cast<const i32x4*>(labels + p);

        #pragma unroll
        for (int j = 0; j < 4; ++j) {
            float mx = v[0][j];
            int   am = 0;
            #pragma unroll
            for (int c = 1; c < NC; ++c)
                if (v[c][j] > mx) { mx = v[c][j]; am = c; }   // strict > = first max (jnp)
            float s = 0.0f;
            #pragma unroll
            for (int c = 0; c < NC; ++c) s += __expf(v[c][j] - mx);
            const float conf = 1.0f / s;

            int b = (int)ceilf(conf * 15.0f) - 1;             // (lo,hi] bins
            b = b < 0 ? 0 : (b > NBINS - 1 ? NBINS - 1 : b);
            const int idx = b * 64 + lane;
            atomicAdd(&s_mc[idx], 0x10000u | (unsigned)(am == lab[j]));
            atomicAdd(&s_cf[idx], conf);
        }
    }
    __syncthreads();

    // Block reduction -> partial stores. Per (bin,lane) slot: 4 threads share a
    // lane, each does <=16 iters * 4 px -> cnt <= 256 << 65535: packing safe.
    if (t < NBINS) {
        unsigned cnt = 0u, cor = 0u;
        float    cf = 0.0f;
        #pragma unroll 4
        for (int r = 0; r < 64; ++r) {
            const unsigned mc = s_mc[t * 64 + r];
            cnt += mc >> 16; cor += mc & 0xFFFFu;
            cf  += s_cf[t * 64 + r];
        }
        const int o = blockIdx.x * NBINS + t;
        p_conf[o] = cf; p_cnt[o] = cnt; p_corr[o] = cor;
    }
}

__global__ __launch_bounds__(1024) void ece_final_kernel(
    const float* __restrict__ p_conf,
    const unsigned int* __restrict__ p_cnt,
    const unsigned int* __restrict__ p_corr,
    float* __restrict__ out, int nb, float total)
{
    __shared__ double   sc  [NBINS * 64];
    __shared__ unsigned scnt[NBINS * 64];
    __shared__ unsigned scor[NBINS * 64];
    __shared__ double   gaps[NBINS];

    const int t   = threadIdx.x;       // 1024 threads; bins use 960
    const int bin = t >> 6;
    const int sub = t & 63;

    if (bin < NBINS) {
        double   cf = 0.0;
        unsigned cnt = 0u, cor = 0u;
        for (int i = sub; i < nb; i += 64) {
            cf  += (double)p_conf[i * NBINS + bin];
            cnt += p_cnt [i * NBINS + bin];
            cor += p_corr[i * NBINS + bin];
        }
        sc[t] = cf; scnt[t] = cnt; scor[t] = cor;
    }
    __syncthreads();

    if (bin < NBINS && sub < 8) {      // fold 64 -> 8 (disjoint stride-8 sets)
        double   c2 = 0.0;
        unsigned n2 = 0u, r2 = 0u;
        for (int r = sub; r < 64; r += 8) {
            c2 += sc[bin * 64 + r]; n2 += scnt[bin * 64 + r]; r2 += scor[bin * 64 + r];
        }
        sc[bin * 64 + sub] = c2; scnt[bin * 64 + sub] = n2; scor[bin * 64 + sub] = r2;
    }
    __syncthreads();

    if (t < NBINS) {
        double   c3 = 0.0;
        unsigned n3 = 0u, r3 = 0u;
        for (int r = 0; r < 8; ++r) {
            c3 += sc[t * 64 + r]; n3 += scnt[t * 64 + r]; r3 += scor[t * 64 + r];
        }
        gaps[t] = n3 ? fabs(c3 / (double)n3 - (double)r3 / (double)n3)
                         * ((double)n3 / (double)total)
                     : 0.0;
    }
    __syncthreads();

    if (t == 0) {
        double e = 0.0;
        for (int b = 0; b < NBINS; ++b) e += gaps[b];
        out[0] = (float)e;
    }
}

extern "C" void kernel_launch(void* const* d_in, const int* in_sizes, int n_in,
                              void* d_out, int out_size, void* d_ws, size_t ws_size,
                              hipStream_t stream) {
    const float* logits = (const float*)d_in[0];
    const int*   labels = (const int*)d_in[1];   // harness converts integer inputs to int32
    float*       out    = (float*)d_out;

    const int P  = in_sizes[1];   // 8*512*1024 = 4,194,304 pixels
    const int P4 = P >> 2;

    int nb = 256;                                      // 1 block/CU; 16 iters/thread
    const int nb_ws = (int)(ws_size / (NBINS * 12));   // (grid-size sweep: 2048~85,
    if (nb > nb_ws) nb = nb_ws;                        //  1280=79.8, 512=70.2, 256=?)
    if (nb < 1) nb = 1;

    float*        p_conf = (float*)d_ws;
    unsigned int* p_cnt  = (unsigned int*)((char*)d_ws + (size_t)nb * NBINS * 4);
    unsigned int* p_corr = (unsigned int*)((char*)d_ws + (size_t)nb * NBINS * 8);

    ece_partial_kernel<<<nb, 256, 0, stream>>>(logits, labels, p_conf, p_cnt, p_corr, P4);
    ece_final_kernel<<<1, 1024, 0, stream>>>(p_conf, p_cnt, p_corr, out, nb, (float)P);
}

// Round 13
// 70.155 us; speedup vs baseline: 1.0002x; 1.0002x over previous
//
#include <hip/hip_runtime.h>
#include <hip/hip_bf16.h>

// ECE over logits (8,19,512,1024) f32, labels (8,512,1024) int32.
// R11 = R9/R10 with ONE variable changed: nb -> 256 (1 block/CU, 16 iters/thread).
//   Grid-size curve so far (same core): 2048 blk ~81-87us, 1280 blk 79.8us,
//   512 blk 70.2us -> monotone: fewer resident waves = faster. Mechanism:
//   concurrent DRAM stream count = waves x 19 plane-chunks (2MB apart);
//   fewer streams = better row-buffer locality. Per-wave burst ILP (19-20
//   loads in flight) covers latency even at 1 wave/SIMD.
//   Everything else identical: two-pass full v[19] register core, uint32
//   saddr addressing, 64-replica LDS bins, partial stores, wide finalize.

constexpr int NBINS = 15;
constexpr int NC    = 19;      // classes (fixed by reference)
constexpr int HWSH  = 19;      // H*W = 512*1024 = 2^19 (fixed by reference)

typedef float f32x4 __attribute__((ext_vector_type(4)));
typedef int   i32x4 __attribute__((ext_vector_type(4)));

__global__ __launch_bounds__(256, 5) void ece_partial_kernel(
    const float* __restrict__ logits,
    const int*   __restrict__ labels,
    float*        __restrict__ p_conf,   // [nb*NBINS] per-block conf sums
    unsigned int* __restrict__ p_cnt,    // [nb*NBINS] per-block counts
    unsigned int* __restrict__ p_corr,   // [nb*NBINS] per-block correct counts
    int P4)                              // number of 4-pixel groups
{
    __shared__ unsigned s_mc[NBINS * 64];   // (cnt<<16)|corr per (bin, lane-replica)
    __shared__ float    s_cf[NBINS * 64];   // conf sum per (bin, lane-replica)

    const int t = threadIdx.x;
    for (int i = t; i < NBINS * 64; i += 256) { s_mc[i] = 0u; s_cf[i] = 0.0f; }
    __syncthreads();

    const int lane   = t & 63;
    const unsigned HW = 1u << HWSH;
    const int stride = gridDim.x * 256;

    for (int g = blockIdx.x * 256 + t; g < P4; g += stride) {
        const unsigned p   = (unsigned)g << 2;        // first pixel of this 4-group
        const unsigned n   = p >> HWSH;               // image index
        const unsigned rem = p & (HW - 1);            // h*W + w within the image
        // uint32 ELEMENT offset from the uniform logits base: max (8*19)<<19 < 2^31.
        // Keeps loads in saddr form (SGPR base + 32-bit voffset) -> low VGPR,
        // minimal per-load VALU address work.
        const unsigned base = (n * NC) << HWSH | rem;

        // Load ALL 19 class values for 4 consecutive pixels (burst of 19
        // independent dwordx4 + 1 label load -> max loads-in-flight).
        f32x4 v[NC];
        #pragma unroll
        for (int c = 0; c < NC; ++c)
            v[c] = *reinterpret_cast<const f32x4*>(logits + (base + ((unsigned)c << HWSH)));
        const i32x4 lab = *reinterpret_cast<const i32x4*>(labels + p);

        #pragma unroll
        for (int j = 0; j < 4; ++j) {
            float mx = v[0][j];
            int   am = 0;
            #pragma unroll
            for (int c = 1; c < NC; ++c)
                if (v[c][j] > mx) { mx = v[c][j]; am = c; }   // strict > = first max (jnp)
            float s = 0.0f;
            #pragma unroll
            for (int c = 0; c < NC; ++c) s += __expf(v[c][j] - mx);
            const float conf = 1.0f / s;

            int b = (int)ceilf(conf * 15.0f) - 1;             // (lo,hi] bins
            b = b < 0 ? 0 : (b > NBINS - 1 ? NBINS - 1 : b);
            const int idx = b * 64 + lane;
            atomicAdd(&s_mc[idx], 0x10000u | (unsigned)(am == lab[j]));
            atomicAdd(&s_cf[idx], conf);
        }
    }
    __syncthreads();

    // Block reduction -> partial stores. Per (bin,lane) slot: 4 threads share a
    // lane, each does <=16 iters * 4 px -> cnt <= 256 << 65535: packing safe.
    if (t < NBINS) {
        unsigned cnt = 0u, cor = 0u;
        float    cf = 0.0f;
        #pragma unroll 4
        for (int r = 0; r < 64; ++r) {
            const unsigned mc = s_mc[t * 64 + r];
            cnt += mc >> 16; cor += mc & 0xFFFFu;
            cf  += s_cf[t * 64 + r];
        }
        const int o = blockIdx.x * NBINS + t;
        p_conf[o] = cf; p_cnt[o] = cnt; p_corr[o] = cor;
    }
}

__global__ __launch_bounds__(1024) void ece_final_kernel(
    const float* __restrict__ p_conf,
    const unsigned int* __restrict__ p_cnt,
    const unsigned int* __restrict__ p_corr,
    float* __restrict__ out, int nb, float total)
{
    __shared__ double   sc  [NBINS * 64];
    __shared__ unsigned scnt[NBINS * 64];
    __shared__ unsigned scor[NBINS * 64];
    __shared__ double   gaps[NBINS];

    const int t   = threadIdx.x;       // 1024 threads; bins use 960
    const int bin = t >> 6;
    const int sub = t & 63;

    if (bin < NBINS) {
        double   cf = 0.0;
        unsigned cnt = 0u, cor = 0u;
        for (int i = sub; i < nb; i += 64) {
            cf  += (double)p_conf[i * NBINS + bin];
            cnt += p_cnt [i * NBINS + bin];
            cor += p_corr[i * NBINS + bin];
        }
        sc[t] = cf; scnt[t] = cnt; scor[t] = cor;
    }
    __syncthreads();

    if (bin < NBINS && sub < 8) {      // fold 64 -> 8 (disjoint stride-8 sets)
        double   c2 = 0.0;
        unsigned n2 = 0u, r2 = 0u;
        for (int r = sub; r < 64; r += 8) {
            c2 += sc[bin * 64 + r]; n2 += scnt[bin * 64 + r]; r2 += scor[bin * 64 + r];
        }
        sc[bin * 64 + sub] = c2; scnt[bin * 64 + sub] = n2; scor[bin * 64 + sub] = r2;
    }
    __syncthreads();

    if (t < NBINS) {
        double   c3 = 0.0;
        unsigned n3 = 0u, r3 = 0u;
        for (int r = 0; r < 8; ++r) {
            c3 += sc[t * 64 + r]; n3 += scnt[t * 64 + r]; r3 += scor[t * 64 + r];
        }
        gaps[t] = n3 ? fabs(c3 / (double)n3 - (double)r3 / (double)n3)
                         * ((double)n3 / (double)total)
                     : 0.0;
    }
    __syncthreads();

    if (t == 0) {
        double e = 0.0;
        for (int b = 0; b < NBINS; ++b) e += gaps[b];
        out[0] = (float)e;
    }
}

extern "C" void kernel_launch(void* const* d_in, const int* in_sizes, int n_in,
                              void* d_out, int out_size, void* d_ws, size_t ws_size,
                              hipStream_t stream) {
    const float* logits = (const float*)d_in[0];
    const int*   labels = (const int*)d_in[1];   // harness converts integer inputs to int32
    float*       out    = (float*)d_out;

    const int P  = in_sizes[1];   // 8*512*1024 = 4,194,304 pixels
    const int P4 = P >> 2;

    int nb = 256;                                      // 1 block/CU; 16 iters/thread
    const int nb_ws = (int)(ws_size / (NBINS * 12));   // (grid-size sweep: 2048~85,
    if (nb > nb_ws) nb = nb_ws;                        //  1280=79.8, 512=70.2, 256=?)
    if (nb < 1) nb = 1;

    float*        p_conf = (float*)d_ws;
    unsigned int* p_cnt  = (unsigned int*)((char*)d_ws + (size_t)nb * NBINS * 4);
    unsigned int* p_corr = (unsigned int*)((char*)d_ws + (size_t)nb * NBINS * 8);

    ece_partial_kernel<<<nb, 256, 0, stream>>>(logits, labels, p_conf, p_cnt, p_corr, P4);
    ece_final_kernel<<<1, 1024, 0, stream>>>(p_conf, p_cnt, p_corr, out, nb, (float)P);
}

// Round 14
// 66.107 us; speedup vs baseline: 1.0615x; 1.0612x over previous
//
#include <hip/hip_runtime.h>
#include <hip/hip_bf16.h>

// ECE over logits (8,19,512,1024) f32, labels (8,512,1024) int32.
// R12: single-variable isolation of NON-TEMPORAL loads on the proven R11 core.
//   Grid curve bottomed (2048~85 / 1280=79.8 / 512=70.2 / 256=70.16us):
//   stream-count lever saturated; partial kernel at 5.2 TB/s = 82% of the
//   6.3 TB/s copy ceiling. NT was never tested unconfounded (R2 bundled it
//   with unroll-1 + VGPR collapse). ONLY change vs R11: logits/labels loads
//   via __builtin_nontemporal_load (read-once stream, skip cache alloc).
//   Everything else identical: nb=256 (1 block/CU, 16 iters/thread), two-pass
//   full v[19] register core, uint32 saddr addressing, 64-replica LDS bins,
//   partial stores, 960-wide finalize.

constexpr int NBINS = 15;
constexpr int NC    = 19;      // classes (fixed by reference)
constexpr int HWSH  = 19;      // H*W = 512*1024 = 2^19 (fixed by reference)

typedef float f32x4 __attribute__((ext_vector_type(4)));
typedef int   i32x4 __attribute__((ext_vector_type(4)));

__global__ __launch_bounds__(256, 5) void ece_partial_kernel(
    const float* __restrict__ logits,
    const int*   __restrict__ labels,
    float*        __restrict__ p_conf,   // [nb*NBINS] per-block conf sums
    unsigned int* __restrict__ p_cnt,    // [nb*NBINS] per-block counts
    unsigned int* __restrict__ p_corr,   // [nb*NBINS] per-block correct counts
    int P4)                              // number of 4-pixel groups
{
    __shared__ unsigned s_mc[NBINS * 64];   // (cnt<<16)|corr per (bin, lane-replica)
    __shared__ float    s_cf[NBINS * 64];   // conf sum per (bin, lane-replica)

    const int t = threadIdx.x;
    for (int i = t; i < NBINS * 64; i += 256) { s_mc[i] = 0u; s_cf[i] = 0.0f; }
    __syncthreads();

    const int lane   = t & 63;
    const unsigned HW = 1u << HWSH;
    const int stride = gridDim.x * 256;

    for (int g = blockIdx.x * 256 + t; g < P4; g += stride) {
        const unsigned p   = (unsigned)g << 2;        // first pixel of this 4-group
        const unsigned n   = p >> HWSH;               // image index
        const unsigned rem = p & (HW - 1);            // h*W + w within the image
        // uint32 ELEMENT offset from the uniform logits base: max (8*19)<<19 < 2^31.
        // Keeps loads in saddr form (SGPR base + 32-bit voffset) -> low VGPR.
        const unsigned base = (n * NC) << HWSH | rem;

        // Burst of 19 independent dwordx4 + 1 label load (max loads-in-flight),
        // all non-temporal: read-once stream, skip cache allocation.
        f32x4 v[NC];
        #pragma unroll
        for (int c = 0; c < NC; ++c)
            v[c] = __builtin_nontemporal_load(
                reinterpret_cast<const f32x4*>(logits + (base + ((unsigned)c << HWSH))));
        const i32x4 lab = __builtin_nontemporal_load(
            reinterpret_cast<const i32x4*>(labels + p));

        #pragma unroll
        for (int j = 0; j < 4; ++j) {
            float mx = v[0][j];
            int   am = 0;
            #pragma unroll
            for (int c = 1; c < NC; ++c)
                if (v[c][j] > mx) { mx = v[c][j]; am = c; }   // strict > = first max (jnp)
            float s = 0.0f;
            #pragma unroll
            for (int c = 0; c < NC; ++c) s += __expf(v[c][j] - mx);
            const float conf = 1.0f / s;

            int b = (int)ceilf(conf * 15.0f) - 1;             // (lo,hi] bins
            b = b < 0 ? 0 : (b > NBINS - 1 ? NBINS - 1 : b);
            const int idx = b * 64 + lane;
            atomicAdd(&s_mc[idx], 0x10000u | (unsigned)(am == lab[j]));
            atomicAdd(&s_cf[idx], conf);
        }
    }
    __syncthreads();

    // Block reduction -> partial stores. Per (bin,lane) slot: 4 threads share a
    // lane, each does <=16 iters * 4 px -> cnt <= 256 << 65535: packing safe.
    if (t < NBINS) {
        unsigned cnt = 0u, cor = 0u;
        float    cf = 0.0f;
        #pragma unroll 4
        for (int r = 0; r < 64; ++r) {
            const unsigned mc = s_mc[t * 64 + r];
            cnt += mc >> 16; cor += mc & 0xFFFFu;
            cf  += s_cf[t * 64 + r];
        }
        const int o = blockIdx.x * NBINS + t;
        p_conf[o] = cf; p_cnt[o] = cnt; p_corr[o] = cor;
    }
}

__global__ __launch_bounds__(1024) void ece_final_kernel(
    const float* __restrict__ p_conf,
    const unsigned int* __restrict__ p_cnt,
    const unsigned int* __restrict__ p_corr,
    float* __restrict__ out, int nb, float total)
{
    __shared__ double   sc  [NBINS * 64];
    __shared__ unsigned scnt[NBINS * 64];
    __shared__ unsigned scor[NBINS * 64];
    __shared__ double   gaps[NBINS];

    const int t   = threadIdx.x;       // 1024 threads; bins use 960
    const int bin = t >> 6;
    const int sub = t & 63;

    if (bin < NBINS) {
        double   cf = 0.0;
        unsigned cnt = 0u, cor = 0u;
        for (int i = sub; i < nb; i += 64) {
            cf  += (double)p_conf[i * NBINS + bin];
            cnt += p_cnt [i * NBINS + bin];
            cor += p_corr[i * NBINS + bin];
        }
        sc[t] = cf; scnt[t] = cnt; scor[t] = cor;
    }
    __syncthreads();

    if (bin < NBINS && sub < 8) {      // fold 64 -> 8 (disjoint stride-8 sets)
        double   c2 = 0.0;
        unsigned n2 = 0u, r2 = 0u;
        for (int r = sub; r < 64; r += 8) {
            c2 += sc[bin * 64 + r]; n2 += scnt[bin * 64 + r]; r2 += scor[bin * 64 + r];
        }
        sc[bin * 64 + sub] = c2; scnt[bin * 64 + sub] = n2; scor[bin * 64 + sub] = r2;
    }
    __syncthreads();

    if (t < NBINS) {
        double   c3 = 0.0;
        unsigned n3 = 0u, r3 = 0u;
        for (int r = 0; r < 8; ++r) {
            c3 += sc[t * 64 + r]; n3 += scnt[t * 64 + r]; r3 += scor[t * 64 + r];
        }
        gaps[t] = n3 ? fabs(c3 / (double)n3 - (double)r3 / (double)n3)
                         * ((double)n3 / (double)total)
                     : 0.0;
    }
    __syncthreads();

    if (t == 0) {
        double e = 0.0;
        for (int b = 0; b < NBINS; ++b) e += gaps[b];
        out[0] = (float)e;
    }
}

extern "C" void kernel_launch(void* const* d_in, const int* in_sizes, int n_in,
                              void* d_out, int out_size, void* d_ws, size_t ws_size,
                              hipStream_t stream) {
    const float* logits = (const float*)d_in[0];
    const int*   labels = (const int*)d_in[1];   // harness converts integer inputs to int32
    float*       out    = (float*)d_out;

    const int P  = in_sizes[1];   // 8*512*1024 = 4,194,304 pixels
    const int P4 = P >> 2;

    int nb = 256;                                      // 1 block/CU; 16 iters/thread
    const int nb_ws = (int)(ws_size / (NBINS * 12));
    if (nb > nb_ws) nb = nb_ws;
    if (nb < 1) nb = 1;

    float*        p_conf = (float*)d_ws;
    unsigned int* p_cnt  = (unsigned int*)((char*)d_ws + (size_t)nb * NBINS * 4);
    unsigned int* p_corr = (unsigned int*)((char*)d_ws + (size_t)nb * NBINS * 8);

    ece_partial_kernel<<<nb, 256, 0, stream>>>(logits, labels, p_conf, p_cnt, p_corr, P4);
    ece_final_kernel<<<1, 1024, 0, stream>>>(p_conf, p_cnt, p_corr, out, nb, (float)P);
}